// Round 1
// baseline (653.300 us; speedup 1.0000x reference)
//
#include <hip/hip_runtime.h>
#include <cstddef>
#include <cstdint>

typedef __bf16 bf16;
typedef __bf16 bf16x8 __attribute__((ext_vector_type(8)));
typedef __bf16 bf16x4 __attribute__((ext_vector_type(4)));
typedef float  f32x4  __attribute__((ext_vector_type(4)));

#define NTOK 49
#define QK_SCALE 0.17677669529663687f  // 32^-0.5

// workspace byte offsets
#define WS_WT   0          // 768*256 bf16 = 393216 B
#define WS_PJT  393216     // 256*256 bf16 = 131072 B
#define WS_P    524288     // 169*8 f32    = 5408 B
#define WS_RPB  532480     // 8*49*49 f32  = 76832 B  (end: 609312)

// ---------------- prep: transpose + bf16-convert weights ----------------
__global__ void prep_weights(const float* __restrict__ qkv_w, const float* __restrict__ proj_w,
                             bf16* __restrict__ wT, bf16* __restrict__ pjT) {
  int tid = blockIdx.x * 256 + threadIdx.x;
  if (tid < 768 * 256) {
    int n = tid >> 8, k = tid & 255;
    wT[tid] = (bf16)qkv_w[k * 768 + n];        // wT[n][k]
  } else {
    int t = tid - 768 * 256;
    int n = t >> 8, k = t & 255;
    pjT[t] = (bf16)proj_w[k * 256 + n];        // pjT[n][k]
  }
}

// ---------------- prep: position-bias MLP (169 rows, tiny) ----------------
__device__ __forceinline__ void mlp_layer(float* p, const float* g, const float* be,
                                          const float* w, const float* bb, int nout) {
  float m = 0.f;
#pragma unroll
  for (int j = 0; j < 16; ++j) m += p[j];
  m *= (1.f / 16.f);
  float v = 0.f;
#pragma unroll
  for (int j = 0; j < 16; ++j) { float d = p[j] - m; v += d * d; }
  v *= (1.f / 16.f);
  float rs = rsqrtf(v + 1e-5f);
  float t[16];
#pragma unroll
  for (int j = 0; j < 16; ++j) {
    float u = (p[j] - m) * rs * g[j] + be[j];
    t[j] = u > 0.f ? u : 0.f;
  }
  float o[16];
  for (int j = 0; j < nout; ++j) {
    float s = bb[j];
#pragma unroll
    for (int k = 0; k < 16; ++k) s += t[k] * w[k * nout + j];
    o[j] = s;
  }
  for (int j = 0; j < nout; ++j) p[j] = o[j];
}

__global__ void pos_mlp(const float* __restrict__ biases, const float* __restrict__ ppw,
                        const float* __restrict__ ppb,
                        const float* g1, const float* be1, const float* w1, const float* bb1,
                        const float* g2, const float* be2, const float* w2, const float* bb2,
                        const float* g3, const float* be3, const float* w3, const float* bb3,
                        float* __restrict__ p_out) {
  int i = blockIdx.x * blockDim.x + threadIdx.x;
  if (i >= 169) return;
  float p[16];
  float y0 = biases[2 * i], y1 = biases[2 * i + 1];
#pragma unroll
  for (int j = 0; j < 16; ++j) p[j] = y0 * ppw[j] + y1 * ppw[16 + j] + ppb[j];
  mlp_layer(p, g1, be1, w1, bb1, 16);
  mlp_layer(p, g2, be2, w2, bb2, 16);
  mlp_layer(p, g3, be3, w3, bb3, 8);
#pragma unroll
  for (int j = 0; j < 8; ++j) p_out[i * 8 + j] = p[j];
}

__global__ void build_rpb(const float* __restrict__ p, const int* __restrict__ rel_idx,
                          float* __restrict__ rpb) {
  int tid = blockIdx.x * 256 + threadIdx.x;
  if (tid >= 8 * 2401) return;
  int h = tid / 2401, rc = tid % 2401;
  rpb[tid] = p[rel_idx[rc] * 8 + h];           // rpb[h][row][col]
}

// ---------------- fused per-window attention ----------------
// block = 256 threads (4 waves) = 1 window. wave w owns heads w and w+4.
// MFMA 16x16x32 bf16 layouts (m89/m92-verified):
//   A-frag: row = lane&15, k = 8*(lane>>4)+j (contiguous -> row-major LDS read)
//   B-frag: col = lane&15, k contiguous      (-> read from transposed/row-major-K)
//   C/D:    col = lane&15, row = 4*(lane>>4)+reg
__launch_bounds__(256)
__global__ void attn_fused(const float* __restrict__ x, const bf16* __restrict__ wT,
                           const float* __restrict__ qkv_b, const bf16* __restrict__ pjT,
                           const float* __restrict__ proj_b, const float* __restrict__ rpb,
                           float* __restrict__ out) {
  __shared__ __align__(16) bf16 x_lds[64 * 264];   // x tile, bf16, pad->264 (2-way banks)
  __shared__ __align__(16) bf16 ao_lds[64 * 264];  // attention output tile
  __shared__ __align__(16) bf16 wbuf[4][7424];     // per-wave: q(64x40)+k(64x40) [P 64x72 overlays], vT 32x72

  const int b = blockIdx.x;
  const int tid = threadIdx.x;
  const int w = tid >> 6;
  const int lane = tid & 63;
  const int lg = lane >> 4;
  const int lr = lane & 15;

  // ---- phase 0: x -> bf16 LDS, rows >= 49 zeroed ----
  const float* xb = x + (size_t)b * (NTOK * 256);
#pragma unroll
  for (int it = 0; it < 16; ++it) {
    int linear = (it * 256 + tid) * 4;
    int r = linear >> 8, c = linear & 255;
    float4 v = make_float4(0.f, 0.f, 0.f, 0.f);
    if (r < NTOK) v = *(const float4*)(xb + r * 256 + c);
    bf16x4 pk;
    pk[0] = (bf16)v.x; pk[1] = (bf16)v.y; pk[2] = (bf16)v.z; pk[3] = (bf16)v.w;
    *(bf16x4*)&x_lds[r * 264 + c] = pk;
  }
  __syncthreads();

  bf16* const q_lds = wbuf[w];
  bf16* const k_lds = wbuf[w] + 2560;
  bf16* const vT    = wbuf[w] + 5120;
  bf16* const P     = wbuf[w];   // overlays q/k once QK^T fragments are in regs

  const f32x4 zero4 = {0.f, 0.f, 0.f, 0.f};

  for (int hi = 0; hi < 2; ++hi) {
    const int h = w + hi * 4;

    // ---- GEMM1: qkv columns for head h (q: n=0,1; k: n=2,3; v: n=4,5) ----
    f32x4 acc[4][6];
#pragma unroll
    for (int m = 0; m < 4; ++m)
#pragma unroll
      for (int n = 0; n < 6; ++n) acc[m][n] = zero4;

#pragma unroll 2
    for (int kk = 0; kk < 8; ++kk) {
      bf16x8 afr[4];
#pragma unroll
      for (int m = 0; m < 4; ++m)
        afr[m] = *(const bf16x8*)&x_lds[(m * 16 + lr) * 264 + kk * 32 + 8 * lg];
#pragma unroll
      for (int n = 0; n < 6; ++n) {
        const int colb = (n < 2) ? (h * 32 + n * 16)
                       : (n < 4) ? (256 + h * 32 + (n - 2) * 16)
                                 : (512 + h * 32 + (n - 4) * 16);
        bf16x8 bfr = *(const bf16x8*)&wT[(size_t)(colb + lr) * 256 + kk * 32 + 8 * lg];
#pragma unroll
        for (int m = 0; m < 4; ++m)
          acc[m][n] = __builtin_amdgcn_mfma_f32_16x16x32_bf16(afr[m], bfr, acc[m][n], 0, 0, 0);
      }
    }

    // ---- bias add; stash q,k row-major and v transposed (packed b64) ----
#pragma unroll
    for (int n = 0; n < 6; ++n) {
      const int colb = (n < 2) ? (h * 32 + n * 16)
                     : (n < 4) ? (256 + h * 32 + (n - 2) * 16)
                               : (512 + h * 32 + (n - 4) * 16);
      const float bias = qkv_b[colb + lr];
      if (n < 4) {
        bf16* dst = (n < 2) ? q_lds : k_lds;
        const int cl = (n & 1) * 16 + lr;
#pragma unroll
        for (int m = 0; m < 4; ++m)
#pragma unroll
          for (int r2 = 0; r2 < 4; ++r2)
            dst[(m * 16 + lg * 4 + r2) * 40 + cl] = (bf16)(acc[m][n][r2] + bias);
      } else {
        const int d = (n - 4) * 16 + lr;
#pragma unroll
        for (int m = 0; m < 4; ++m) {
          bf16x4 pk;
#pragma unroll
          for (int r2 = 0; r2 < 4; ++r2) pk[r2] = (bf16)(acc[m][n][r2] + bias);
          *(bf16x4*)&vT[d * 72 + m * 16 + lg * 4] = pk;   // vT[d][token]
        }
      }
    }

    // ---- QK^T (K = head_dim = 32, single k-step) ----
    bf16x8 aq[4], bk[4];
#pragma unroll
    for (int m = 0; m < 4; ++m) aq[m] = *(const bf16x8*)&q_lds[(m * 16 + lr) * 40 + 8 * lg];
#pragma unroll
    for (int n = 0; n < 4; ++n) bk[n] = *(const bf16x8*)&k_lds[(n * 16 + lr) * 40 + 8 * lg];
    f32x4 s[4][4];
#pragma unroll
    for (int m = 0; m < 4; ++m)
#pragma unroll
      for (int n = 0; n < 4; ++n)
        s[m][n] = __builtin_amdgcn_mfma_f32_16x16x32_bf16(aq[m], bk[n], zero4, 0, 0, 0);

    // ---- scale + rel-pos bias + key mask ----
    const float* rpbh = rpb + h * 2401;
#pragma unroll
    for (int m = 0; m < 4; ++m)
#pragma unroll
      for (int n = 0; n < 4; ++n) {
        const int col = n * 16 + lr;
#pragma unroll
        for (int r2 = 0; r2 < 4; ++r2) {
          const int row = m * 16 + lg * 4 + r2;
          float val = s[m][n][r2] * QK_SCALE;
          if (col < NTOK) {
            if (row < NTOK) val += rpbh[row * 49 + col];
          } else {
            val = -1e30f;   // padded keys
          }
          s[m][n][r2] = val;
        }
      }

    // ---- softmax: per-row reduce over 16-lane groups (4 shfl_xor steps) ----
    float inv[4][4];
#pragma unroll
    for (int m = 0; m < 4; ++m)
#pragma unroll
      for (int r2 = 0; r2 < 4; ++r2) {
        float mx = fmaxf(fmaxf(s[m][0][r2], s[m][1][r2]), fmaxf(s[m][2][r2], s[m][3][r2]));
#pragma unroll
        for (int off = 1; off <= 8; off <<= 1) mx = fmaxf(mx, __shfl_xor(mx, off, 64));
        float sum = 0.f;
#pragma unroll
        for (int n = 0; n < 4; ++n) {
          float e = __expf(s[m][n][r2] - mx);
          s[m][n][r2] = e;
          sum += e;
        }
#pragma unroll
        for (int off = 1; off <= 8; off <<= 1) sum += __shfl_xor(sum, off, 64);
        inv[m][r2] = 1.f / sum;
      }

    // ---- P -> LDS (row-major bf16; overlays dead q/k region) ----
#pragma unroll
    for (int m = 0; m < 4; ++m)
#pragma unroll
      for (int n = 0; n < 4; ++n)
#pragma unroll
        for (int r2 = 0; r2 < 4; ++r2)
          P[(m * 16 + lg * 4 + r2) * 72 + n * 16 + lr] = (bf16)s[m][n][r2];

    // ---- PV: out_h = P(64x64) @ v(64x32) ----
    f32x4 o[4][2];
#pragma unroll
    for (int m = 0; m < 4; ++m)
#pragma unroll
      for (int n2 = 0; n2 < 2; ++n2) o[m][n2] = zero4;
#pragma unroll
    for (int ks = 0; ks < 2; ++ks) {
      bf16x8 ap[4], bv[2];
#pragma unroll
      for (int m = 0; m < 4; ++m) ap[m] = *(const bf16x8*)&P[(m * 16 + lr) * 72 + ks * 32 + 8 * lg];
#pragma unroll
      for (int n2 = 0; n2 < 2; ++n2) bv[n2] = *(const bf16x8*)&vT[(n2 * 16 + lr) * 72 + ks * 32 + 8 * lg];
#pragma unroll
      for (int m = 0; m < 4; ++m)
#pragma unroll
        for (int n2 = 0; n2 < 2; ++n2)
          o[m][n2] = __builtin_amdgcn_mfma_f32_16x16x32_bf16(ap[m], bv[n2], o[m][n2], 0, 0, 0);
    }

    // ---- normalize rows, write head's slice of attn-out tile ----
#pragma unroll
    for (int m = 0; m < 4; ++m)
#pragma unroll
      for (int n2 = 0; n2 < 2; ++n2)
#pragma unroll
        for (int r2 = 0; r2 < 4; ++r2)
          ao_lds[(m * 16 + lg * 4 + r2) * 264 + h * 32 + n2 * 16 + lr] =
              (bf16)(o[m][n2][r2] * inv[m][r2]);
  }
  __syncthreads();

  // ---- proj: out = ao(64x256) @ proj_w(256x256) + b; wave w owns 64 output cols ----
  f32x4 c2[4][4];
#pragma unroll
  for (int m = 0; m < 4; ++m)
#pragma unroll
    for (int n = 0; n < 4; ++n) c2[m][n] = zero4;
#pragma unroll 2
  for (int kk = 0; kk < 8; ++kk) {
    bf16x8 afr[4];
#pragma unroll
    for (int m = 0; m < 4; ++m)
      afr[m] = *(const bf16x8*)&ao_lds[(m * 16 + lr) * 264 + kk * 32 + 8 * lg];
#pragma unroll
    for (int n = 0; n < 4; ++n) {
      bf16x8 bfr = *(const bf16x8*)&pjT[(size_t)(w * 64 + n * 16 + lr) * 256 + kk * 32 + 8 * lg];
#pragma unroll
      for (int m = 0; m < 4; ++m)
        c2[m][n] = __builtin_amdgcn_mfma_f32_16x16x32_bf16(afr[m], bfr, c2[m][n], 0, 0, 0);
    }
  }
  float* ob = out + (size_t)b * (NTOK * 256);
#pragma unroll
  for (int n = 0; n < 4; ++n) {
    const int col = w * 64 + n * 16 + lr;
    const float pb = proj_b[col];
#pragma unroll
    for (int m = 0; m < 4; ++m)
#pragma unroll
      for (int r2 = 0; r2 < 4; ++r2) {
        const int row = m * 16 + lg * 4 + r2;
        if (row < NTOK) ob[row * 256 + col] = c2[m][n][r2] + pb;
      }
  }
}

// ---------------- launcher ----------------
extern "C" void kernel_launch(void* const* d_in, const int* in_sizes, int n_in,
                              void* d_out, int out_size, void* d_ws, size_t ws_size,
                              hipStream_t stream) {
  (void)in_sizes; (void)n_in; (void)out_size; (void)ws_size;
  const float* x      = (const float*)d_in[0];
  const float* qkv_w  = (const float*)d_in[1];
  const float* qkv_b  = (const float*)d_in[2];
  const float* proj_w = (const float*)d_in[3];
  const float* proj_b = (const float*)d_in[4];
  const float* ppw    = (const float*)d_in[5];
  const float* ppb    = (const float*)d_in[6];
  const float* ln1_g  = (const float*)d_in[7];
  const float* ln1_b  = (const float*)d_in[8];
  const float* w1     = (const float*)d_in[9];
  const float* b1     = (const float*)d_in[10];
  const float* ln2_g  = (const float*)d_in[11];
  const float* ln2_b  = (const float*)d_in[12];
  const float* w2     = (const float*)d_in[13];
  const float* b2     = (const float*)d_in[14];
  const float* ln3_g  = (const float*)d_in[15];
  const float* ln3_b  = (const float*)d_in[16];
  const float* w3     = (const float*)d_in[17];
  const float* b3     = (const float*)d_in[18];
  const float* biases = (const float*)d_in[19];
  const int*   relidx = (const int*)d_in[20];

  char* ws = (char*)d_ws;
  bf16*  wT   = (bf16*)(ws + WS_WT);
  bf16*  pjT  = (bf16*)(ws + WS_PJT);
  float* p_ws = (float*)(ws + WS_P);
  float* rpb  = (float*)(ws + WS_RPB);

  prep_weights<<<1024, 256, 0, stream>>>(qkv_w, proj_w, wT, pjT);
  pos_mlp<<<1, 256, 0, stream>>>(biases, ppw, ppb,
                                 ln1_g, ln1_b, w1, b1,
                                 ln2_g, ln2_b, w2, b2,
                                 ln3_g, ln3_b, w3, b3, p_ws);
  build_rpb<<<76, 256, 0, stream>>>(p_ws, relidx, rpb);
  attn_fused<<<4096, 256, 0, stream>>>(x, wT, qkv_b, pjT, proj_b, rpb, (float*)d_out);
}